// Round 3
// baseline (56.875 us; speedup 1.0000x reference)
//
#include <hip/hip_runtime.h>

// Problem constants (fixed by the reference):
//   B=64, L=2048, D=1024, seq f32, begin/end int32 (harness downcasts int64),
//   out f32 [B, D]
#define B_ 64
#define L_ 2048
#define D_ 1024
#define G_ 2048   // blocks: perfectly balanced ragged-row partition

__global__ __launch_bounds__(256) void zero_out_kernel(float* __restrict__ out) {
    int i = blockIdx.x * blockDim.x + threadIdx.x;
    if (i < B_ * D_) out[i] = 0.0f;
}

__global__ __launch_bounds__(256) void seg_mean_bal_kernel(
    const float* __restrict__ seq,
    const int* __restrict__ begin,
    const int* __restrict__ end,
    float* __restrict__ out)
{
    // Total ragged rows T (64 broadcast loads; L1-cached after first block).
    int T = 0;
    #pragma unroll
    for (int b = 0; b < B_; ++b) T += end[b] - begin[b];

    const int k  = blockIdx.x;
    const int r0 = (int)(((long long)k * T) / G_);
    const int r1 = (int)(((long long)(k + 1) * T) / G_);
    if (r0 >= r1) return;

    // Find the batch containing global ragged row r0.
    int b = 0, acc = 0;
    for (;;) {
        int len = end[b] - begin[b];
        if (acc + len > r0) break;
        acc += len; ++b;
    }

    const int col = threadIdx.x;  // one float4 of the D=1024 row

    int r = r0;
    while (r < r1) {
        const int len     = end[b] - begin[b];
        const int seg_end = min(r1, acc + len);   // global row end of this batch segment
        int       l       = begin[b] + (r - acc); // local row in batch b
        const int l_end   = l + (seg_end - r);

        const float4* __restrict__ base =
            reinterpret_cast<const float4*>(seq + (size_t)b * L_ * D_);

        float4 a0 = make_float4(0.f, 0.f, 0.f, 0.f);
        float4 a1 = a0, a2 = a0, a3 = a0;

        // 4-deep unroll: 4 independent 16B loads in flight per thread
        for (; l + 4 <= l_end; l += 4) {
            float4 v0 = base[(size_t)(l + 0) * (D_ / 4) + col];
            float4 v1 = base[(size_t)(l + 1) * (D_ / 4) + col];
            float4 v2 = base[(size_t)(l + 2) * (D_ / 4) + col];
            float4 v3 = base[(size_t)(l + 3) * (D_ / 4) + col];
            a0.x += v0.x; a0.y += v0.y; a0.z += v0.z; a0.w += v0.w;
            a1.x += v1.x; a1.y += v1.y; a1.z += v1.z; a1.w += v1.w;
            a2.x += v2.x; a2.y += v2.y; a2.z += v2.z; a2.w += v2.w;
            a3.x += v3.x; a3.y += v3.y; a3.z += v3.z; a3.w += v3.w;
        }
        for (; l < l_end; ++l) {
            float4 v = base[(size_t)l * (D_ / 4) + col];
            a0.x += v.x; a0.y += v.y; a0.z += v.z; a0.w += v.w;
        }

        // Pre-scale by 1/count so atomics accumulate the mean directly.
        const float inv = 1.0f / (float)len;
        float tx = (a0.x + a1.x + a2.x + a3.x) * inv;
        float ty = (a0.y + a1.y + a2.y + a3.y) * inv;
        float tz = (a0.z + a1.z + a2.z + a3.z) * inv;
        float tw = (a0.w + a1.w + a2.w + a3.w) * inv;

        float* o = out + (size_t)b * D_ + (size_t)col * 4;
        atomicAdd(o + 0, tx);
        atomicAdd(o + 1, ty);
        atomicAdd(o + 2, tz);
        atomicAdd(o + 3, tw);

        // Advance to next batch segment.
        r = seg_end; acc += len; ++b;
    }
}

extern "C" void kernel_launch(void* const* d_in, const int* in_sizes, int n_in,
                              void* d_out, int out_size, void* d_ws, size_t ws_size,
                              hipStream_t stream) {
    const float* seq   = (const float*)d_in[0];
    const int*   begin = (const int*)d_in[1];   // int32: harness downcasts jnp.int64
    const int*   end   = (const int*)d_in[2];
    float*       out   = (float*)d_out;

    // d_out is poisoned (0xAA) before timing; zero it each call (atomics accumulate).
    zero_out_kernel<<<(B_ * D_ + 255) / 256, 256, 0, stream>>>(out);

    seg_mean_bal_kernel<<<G_, 256, 0, stream>>>(seq, begin, end, out);
}

// Round 4
// 34.712 us; speedup vs baseline: 1.6385x; 1.6385x over previous
//
#include <hip/hip_runtime.h>

// Problem constants (fixed by the reference):
//   B=64, L=2048, D=1024, seq f32, begin/end int32 (harness downcasts int64),
//   out f32 [B, D]
#define B_ 64
#define L_ 2048
#define D_ 1024
#define SPLIT 32   // span slices per batch -> stage1 grid 64x32 = 2048 blocks

// Stage 1: block (b,s) accumulates rows [bg + s*per, ...) of batch b and
// stores a pre-scaled partial (zeros if slice empty) to ws[b][s][0..D).
// Plain float4 stores — NO atomics.
__global__ __launch_bounds__(256) void seg_mean_stage1(
    const float* __restrict__ seq,
    const int* __restrict__ begin,
    const int* __restrict__ end,
    float* __restrict__ ws)
{
    const int b  = blockIdx.x;
    const int s  = blockIdx.y;
    const int bg = begin[b];
    const int en = end[b];
    const int len = en - bg;             // >= 1

    const int per = (len + SPLIT - 1) / SPLIT;
    const int l0  = bg + s * per;
    const int l1  = min(l0 + per, en);

    const int col = threadIdx.x;         // one float4 of the D=1024 row
    const float4* __restrict__ base =
        reinterpret_cast<const float4*>(seq + (size_t)b * L_ * D_);

    float4 a0 = make_float4(0.f, 0.f, 0.f, 0.f);
    float4 a1 = a0, a2 = a0, a3 = a0;

    int l = l0;
    for (; l + 4 <= l1; l += 4) {        // 4 independent 16B loads in flight
        float4 v0 = base[(size_t)(l + 0) * (D_ / 4) + col];
        float4 v1 = base[(size_t)(l + 1) * (D_ / 4) + col];
        float4 v2 = base[(size_t)(l + 2) * (D_ / 4) + col];
        float4 v3 = base[(size_t)(l + 3) * (D_ / 4) + col];
        a0.x += v0.x; a0.y += v0.y; a0.z += v0.z; a0.w += v0.w;
        a1.x += v1.x; a1.y += v1.y; a1.z += v1.z; a1.w += v1.w;
        a2.x += v2.x; a2.y += v2.y; a2.z += v2.z; a2.w += v2.w;
        a3.x += v3.x; a3.y += v3.y; a3.z += v3.z; a3.w += v3.w;
    }
    for (; l < l1; ++l) {
        float4 v = base[(size_t)l * (D_ / 4) + col];
        a0.x += v.x; a0.y += v.y; a0.z += v.z; a0.w += v.w;
    }

    const float inv = 1.0f / (float)len; // pre-scale so stage2 is a plain sum
    float4 t;
    t.x = (a0.x + a1.x + a2.x + a3.x) * inv;
    t.y = (a0.y + a1.y + a2.y + a3.y) * inv;
    t.z = (a0.z + a1.z + a2.z + a3.z) * inv;
    t.w = (a0.w + a1.w + a2.w + a3.w) * inv;

    float4* __restrict__ w4 = reinterpret_cast<float4*>(ws);
    w4[((size_t)(b * SPLIT + s)) * (D_ / 4) + col] = t;   // unconditional
}

// Stage 2: block b, thread col sums ws[b][0..SPLIT)[col4] and overwrites out.
__global__ __launch_bounds__(256) void seg_mean_stage2(
    const float* __restrict__ ws,
    float* __restrict__ out)
{
    const int b   = blockIdx.x;
    const int col = threadIdx.x;
    const float4* __restrict__ w4 =
        reinterpret_cast<const float4*>(ws) + (size_t)b * SPLIT * (D_ / 4);

    float4 acc = make_float4(0.f, 0.f, 0.f, 0.f);
    #pragma unroll
    for (int s = 0; s < SPLIT; ++s) {
        float4 v = w4[(size_t)s * (D_ / 4) + col];
        acc.x += v.x; acc.y += v.y; acc.z += v.z; acc.w += v.w;
    }
    reinterpret_cast<float4*>(out)[(size_t)b * (D_ / 4) + col] = acc;
}

extern "C" void kernel_launch(void* const* d_in, const int* in_sizes, int n_in,
                              void* d_out, int out_size, void* d_ws, size_t ws_size,
                              hipStream_t stream) {
    const float* seq   = (const float*)d_in[0];
    const int*   begin = (const int*)d_in[1];   // int32: harness downcasts jnp.int64
    const int*   end   = (const int*)d_in[2];
    float*       out   = (float*)d_out;
    float*       ws    = (float*)d_ws;          // needs 64*32*1024*4 = 8 MB

    dim3 g1(B_, SPLIT);
    seg_mean_stage1<<<g1, 256, 0, stream>>>(seq, begin, end, ws);
    seg_mean_stage2<<<B_, 256, 0, stream>>>(ws, out);
}